// Round 1
// baseline (227.073 us; speedup 1.0000x reference)
//
#include <hip/hip_runtime.h>
#include <hip/hip_bf16.h>

typedef float f32x4 __attribute__((ext_vector_type(4)));
typedef __bf16 bf16x8 __attribute__((ext_vector_type(8)));
typedef unsigned short u16;

// ---------------- fp32 -> bf16 (RNE) ----------------
__device__ inline u16 f2bf(float f) {
    unsigned int u = __float_as_uint(f);
    unsigned int r = (u + 0x7fffu + ((u >> 16) & 1u)) >> 16;
    return (u16)r;
}

// Convert node embeddings fp32 -> bf16, 4 floats/thread.
__global__ __launch_bounds__(256) void cvt_emb_kernel(const float* __restrict__ in,
                                                      u16* __restrict__ out, int n4) {
    int i = blockIdx.x * blockDim.x + threadIdx.x;
    if (i >= n4) return;
    float4 v = ((const float4*)in)[i];
    unsigned int lo = (unsigned int)f2bf(v.x) | ((unsigned int)f2bf(v.y) << 16);
    unsigned int hi = (unsigned int)f2bf(v.z) | ((unsigned int)f2bf(v.w) << 16);
    uint2 o; o.x = lo; o.y = hi;
    ((uint2*)out)[i] = o;
}

// W1 [256][64] fp32 row-major -> W1^T bf16 [64][256]
__global__ __launch_bounds__(256) void cvt_w1_kernel(const float* __restrict__ W1,
                                                     u16* __restrict__ w1t) {
    for (int i = threadIdx.x; i < 256 * 64; i += 256) {
        int n = i >> 8, k = i & 255;
        w1t[i] = f2bf(W1[k * 64 + n]);
    }
}

// ---------------- main fused kernel ----------------
// Each wave owns 16 edges per tile. Block = 4 waves = 64 edges/tile.
// LDS: per-wave-private 16 edges x 256 bf16 (concat src|tgt), XOR-swizzled so
// that (a) global_load_lds lane-contiguous DMA works, (b) A-frag ds_read_b128
// lands as uniform 2-way bank aliasing (free).
__global__ __launch_bounds__(256, 2) void edge_mlp_kernel(
    const u16* __restrict__ emb,   // [N][128] bf16
    const int* __restrict__ idx,   // [2][E]
    const u16* __restrict__ w1t,   // [64][256] bf16
    const float* __restrict__ b1,  // [64]
    const float* __restrict__ w2,  // [64]
    const float* __restrict__ b2,  // [1]
    float* __restrict__ out,       // [E]
    int E, int nTiles) {
    __shared__ __align__(16) u16 feat[64 * 256];  // 32 KB

    const int tid  = threadIdx.x;
    const int w    = tid >> 6;
    const int lane = tid & 63;
    const int quad = lane >> 4;
    const int l15  = lane & 15;

    // B fragments held in registers for the whole (persistent) block:
    // bfrag[kb][t]: lane holds B[k = kb*32 + quad*8 + j][n = t*16 + l15]
    bf16x8 bfrag[8][4];
#pragma unroll
    for (int t = 0; t < 4; ++t) {
        const u16* bp = w1t + (t * 16 + l15) * 256 + quad * 8;
#pragma unroll
        for (int kb = 0; kb < 8; ++kb)
            bfrag[kb][t] = *(const bf16x8*)(bp + kb * 32);
    }
    float b1v[4], w2v[4];
#pragma unroll
    for (int t = 0; t < 4; ++t) {
        b1v[t] = b1[t * 16 + l15];
        w2v[t] = w2[t * 16 + l15];
    }
    const float b2v = b2[0];

    u16* featW = feat + w * 16 * 256;  // wave-private 8 KB region

    for (int tile = blockIdx.x; tile < nTiles; tile += gridDim.x) {
        const int ebase = tile * 64 + w * 16;

        // lanes 0..15: src index of edge l15; lanes 16..31: tgt index
        int idxv = 0;
        if (lane < 32) {
            int ge = ebase + l15;
            if (ge >= E) ge = E - 1;
            idxv = idx[quad * E + ge];  // quad==half for lanes<32
        }

        // Stage 16 edges x 512 B via global_load_lds (8 passes x 1 KB/wave).
        // slot q = e*32 + (c ^ (e&7)); content = feature[e][16B-chunk c]
#pragma unroll
        for (int p = 0; p < 8; ++p) {
            int q    = p * 64 + lane;
            int e    = q >> 5;                 // 0..15 local edge
            int c    = (q & 31) ^ (e & 7);     // de-swizzled chunk
            int half = c >> 4;                 // 0 = src, 1 = tgt
            int j    = c & 15;                 // 16B chunk within row
            int node = __shfl(idxv, half * 16 + e, 64);
            const u16* g = emb + (long)node * 128 + j * 8;
            __builtin_amdgcn_global_load_lds(
                (const __attribute__((address_space(1))) void*)g,
                (__attribute__((address_space(3))) void*)(featW + p * 64 * 8),
                16, 0, 0);
        }
        __syncthreads();  // drain DMA (vmcnt) + block convergence

        f32x4 acc[4];
#pragma unroll
        for (int t = 0; t < 4; ++t)
#pragma unroll
            for (int r = 0; r < 4; ++r) acc[t][r] = 0.0f;

#pragma unroll
        for (int kb = 0; kb < 8; ++kb) {
            int c = kb * 4 + quad;
            int q = l15 * 32 + (c ^ (l15 & 7));
            bf16x8 a = *(const bf16x8*)(featW + q * 8);
#pragma unroll
            for (int t = 0; t < 4; ++t)
                acc[t] = __builtin_amdgcn_mfma_f32_16x16x32_bf16(a, bfrag[kb][t],
                                                                 acc[t], 0, 0, 0);
        }

        // Epilogue: h = relu(acc + b1); partial score = sum_n h*w2 over this
        // lane's columns; then shfl-xor reduce over the 16 cols in the group.
        float p0 = 0.f, p1 = 0.f, p2 = 0.f, p3 = 0.f;
#pragma unroll
        for (int t = 0; t < 4; ++t) {
            float h;
            h = acc[t][0] + b1v[t]; p0 += (h > 0.f) ? h * w2v[t] : 0.f;
            h = acc[t][1] + b1v[t]; p1 += (h > 0.f) ? h * w2v[t] : 0.f;
            h = acc[t][2] + b1v[t]; p2 += (h > 0.f) ? h * w2v[t] : 0.f;
            h = acc[t][3] + b1v[t]; p3 += (h > 0.f) ? h * w2v[t] : 0.f;
        }
#pragma unroll
        for (int m = 1; m <= 8; m <<= 1) {
            p0 += __shfl_xor(p0, m, 64);
            p1 += __shfl_xor(p1, m, 64);
            p2 += __shfl_xor(p2, m, 64);
            p3 += __shfl_xor(p3, m, 64);
        }
        // rows: e = quad*4 + r  (C layout: col=l15, row=quad*4+reg)
        if (l15 < 4) {
            float v = ((l15 == 0) ? p0 : (l15 == 1) ? p1 : (l15 == 2) ? p2 : p3) + b2v;
            int eo = ebase + quad * 4 + l15;
            if (eo < E) out[eo] = v;
        }
        __syncthreads();  // feat reuse next tile (cheap; waves symmetric)
    }
}

extern "C" void kernel_launch(void* const* d_in, const int* in_sizes, int n_in,
                              void* d_out, int out_size, void* d_ws, size_t ws_size,
                              hipStream_t stream) {
    const float* emb_f = (const float*)d_in[0];
    const int*   idx   = (const int*)d_in[1];
    const float* W1    = (const float*)d_in[2];
    const float* b1    = (const float*)d_in[3];
    const float* W2    = (const float*)d_in[4];
    const float* b2    = (const float*)d_in[5];
    float* out = (float*)d_out;

    const int embN = in_sizes[0];       // N_NODES * 128
    const int E    = in_sizes[1] / 2;

    u16* emb_bf = (u16*)d_ws;
    u16* w1t    = emb_bf + embN;        // 32 KB right after embeddings

    int n4 = embN / 4;
    cvt_emb_kernel<<<(n4 + 255) / 256, 256, 0, stream>>>(emb_f, emb_bf, n4);
    cvt_w1_kernel<<<1, 256, 0, stream>>>(W1, w1t);

    int nTiles = (E + 63) / 64;
    edge_mlp_kernel<<<1024, 256, 0, stream>>>(emb_bf, idx, w1t, b1, W2, b2, out,
                                              E, nTiles);
}